// Round 1
// baseline (2923.595 us; speedup 1.0000x reference)
//
#include <hip/hip_runtime.h>
#include <cstddef>
#include <cstdint>

#define GAMMA_F 0.99f
#define OMG_F   0.01f      // 1 - gamma
#define EPS_F   1e-5f
#define KN 8192
#define DD 256
#define NN 32768           // B*T = 32*1024

// output layout (float offsets)
#define OFF_ZQ     0
#define OFF_COMMIT 8388608
#define OFF_IDX    8388609
#define OFF_EMB    8421377
#define OFF_MT     10518529
#define OFF_NT     12615681

// ---------------------------------------------------------------------------
// ||w_k||^2 per code. One wave per code row.
__global__ __launch_bounds__(64) void wsq_kernel(const float* __restrict__ W,
                                                 float* __restrict__ wsq) {
    const int k = blockIdx.x;
    const int lane = threadIdx.x;
    const float4 v = *(const float4*)(W + (size_t)k * DD + lane * 4);
    float s = v.x * v.x + v.y * v.y + v.z * v.z + v.w * v.w;
#pragma unroll
    for (int off = 32; off > 0; off >>= 1) s += __shfl_down(s, off, 64);
    if (lane == 0) wsq[k] = s;
}

// ---------------------------------------------------------------------------
// Fused distance-GEMM + argmin.
// Block: 256 threads, tile 64 points x 64 codes, D chunked by 64.
// dist = ||w||^2 - 2*z.w  (||z||^2 dropped: constant per point under argmin)
#define TM 64
#define TK 64
#define TD 64
#define LDP 68   // padded LDS row stride (floats), keeps float4 alignment

__global__ __launch_bounds__(256) void argmin_kernel(
    const float* __restrict__ ze, const float* __restrict__ W,
    const float* __restrict__ wsq, float* __restrict__ out_idx) {
    __shared__ float zt[TD][LDP];   // [d][point]
    __shared__ float wt[TD][LDP];   // [d][code]

    const int tid = threadIdx.x;
    const int tx = tid & 15;        // code group
    const int ty = tid >> 4;        // point group
    const int n0 = blockIdx.x * TM;
    const int srow = tid >> 4;      // staging row base (0..15)
    const int scol = (tid & 15) * 4;

    float bestv[4];
    int   besti[4];
#pragma unroll
    for (int i = 0; i < 4; i++) { bestv[i] = 3.4e38f; besti[i] = 0; }

    for (int kc = 0; kc < KN; kc += TK) {
        float dot[4][4];
#pragma unroll
        for (int i = 0; i < 4; i++)
#pragma unroll
            for (int j = 0; j < 4; j++) dot[i][j] = 0.0f;

        for (int dc = 0; dc < DD; dc += TD) {
            __syncthreads();   // protect tiles from previous iteration's readers
#pragma unroll
            for (int r = 0; r < 4; r++) {
                const int row = srow + r * 16;
                const float4 v = *(const float4*)(ze + (size_t)(n0 + row) * DD + dc + scol);
                zt[scol + 0][row] = v.x;
                zt[scol + 1][row] = v.y;
                zt[scol + 2][row] = v.z;
                zt[scol + 3][row] = v.w;
                const float4 u = *(const float4*)(W + (size_t)(kc + row) * DD + dc + scol);
                wt[scol + 0][row] = u.x;
                wt[scol + 1][row] = u.y;
                wt[scol + 2][row] = u.z;
                wt[scol + 3][row] = u.w;
            }
            __syncthreads();

#pragma unroll 4
            for (int d = 0; d < TD; d++) {
                float a[4], b[4];
                *(float4*)a = *(const float4*)(&zt[d][ty * 4]);
                *(float4*)b = *(const float4*)(&wt[d][tx * 4]);
#pragma unroll
                for (int i = 0; i < 4; i++)
#pragma unroll
                    for (int j = 0; j < 4; j++) dot[i][j] += a[i] * b[j];
            }
        }

#pragma unroll
        for (int j = 0; j < 4; j++) {
            const int c = kc + tx * 4 + j;
            const float w2 = wsq[c];
#pragma unroll
            for (int i = 0; i < 4; i++) {
                const float dist = w2 - 2.0f * dot[i][j];
                // strict <  => keeps earliest (lowest) code on exact ties,
                // matching jnp.argmin first-occurrence semantics
                if (dist < bestv[i] || (dist == bestv[i] && c < besti[i])) {
                    bestv[i] = dist;
                    besti[i] = c;
                }
            }
        }
    }

    // threads sharing the same 4 points are the 16 contiguous lanes with equal ty
#pragma unroll
    for (int off = 1; off < 16; off <<= 1) {
#pragma unroll
        for (int i = 0; i < 4; i++) {
            const float ov = __shfl_xor(bestv[i], off, 64);
            const int   oi = __shfl_xor(besti[i], off, 64);
            if (ov < bestv[i] || (ov == bestv[i] && oi < besti[i])) {
                bestv[i] = ov;
                besti[i] = oi;
            }
        }
    }
    if (tx == 0) {
#pragma unroll
        for (int i = 0; i < 4; i++)
            out_idx[n0 + ty * 4 + i] = (float)besti[i];
    }
}

// ---------------------------------------------------------------------------
// Gather zq, write zq_st, commit-loss reduce, and one-hot scatter (atomics).
// One wave per point; 4 points per 256-thread block.
__global__ __launch_bounds__(256) void gather_scatter_kernel(
    const float* __restrict__ ze, const float* __restrict__ W,
    const float* __restrict__ idxf, float* __restrict__ zq_out,
    float* __restrict__ commit_acc, float* __restrict__ mt_acc,
    float* __restrict__ nt_acc) {
    const int tid = threadIdx.x;
    const int n = blockIdx.x * 4 + (tid >> 6);
    const int lane = tid & 63;
    const int idx = (int)idxf[n];

    const float4 z = *(const float4*)(ze + (size_t)n * DD + lane * 4);
    const float4 w = *(const float4*)(W + (size_t)idx * DD + lane * 4);

    float4 d, o;
    d.x = w.x - z.x; d.y = w.y - z.y; d.z = w.z - z.z; d.w = w.w - z.w;
    o.x = z.x + d.x; o.y = z.y + d.y; o.z = z.z + d.z; o.w = z.w + d.w;
    *(float4*)(zq_out + (size_t)n * DD + lane * 4) = o;

    float* mp = mt_acc + (size_t)idx * DD + lane * 4;
    atomicAdd(mp + 0, OMG_F * z.x);
    atomicAdd(mp + 1, OMG_F * z.y);
    atomicAdd(mp + 2, OMG_F * z.z);
    atomicAdd(mp + 3, OMG_F * z.w);
    if (lane == 0) atomicAdd(nt_acc + idx, OMG_F);

    float c = d.x * d.x + d.y * d.y + d.z * d.z + d.w * d.w;
#pragma unroll
    for (int off = 32; off > 0; off >>= 1) c += __shfl_down(c, off, 64);

    __shared__ float wsum[4];
    if (lane == 0) wsum[tid >> 6] = c;
    __syncthreads();
    if (tid == 0) {
        const float part = wsum[0] + wsum[1] + wsum[2] + wsum[3];
        atomicAdd(commit_acc, part * (1.0f / 8388608.0f));  // N*D = 2^23 exact
    }
}

// ---------------------------------------------------------------------------
// Nt_new = gamma*Nt + (already accumulated) 0.01*nt
__global__ __launch_bounds__(256) void finalize_nt_kernel(
    const float* __restrict__ Nt_in, float* __restrict__ nt_acc) {
    const int k = blockIdx.x * 256 + threadIdx.x;
    nt_acc[k] += GAMMA_F * Nt_in[k];
}

// ---------------------------------------------------------------------------
// mt_new = gamma*mt + 0.01*st (st already accumulated in mt_out);
// n = sum(Nt_new); Nn = (Nt_new+eps)*n/(n+K*eps); embedW_new = mt_new/Nn.
__global__ __launch_bounds__(256) void final_kernel(
    const float* __restrict__ mt_in, const float* __restrict__ nt_new,
    float* __restrict__ mt_out, float* __restrict__ emb_out) {
    __shared__ float red[256];
    float s = 0.0f;
    for (int i = threadIdx.x; i < KN; i += 256) s += nt_new[i];
    red[threadIdx.x] = s;
    __syncthreads();
    for (int off = 128; off > 0; off >>= 1) {
        if (threadIdx.x < off) red[threadIdx.x] += red[threadIdx.x + off];
        __syncthreads();
    }
    const float n = red[0];

    const size_t i0 = ((size_t)blockIdx.x * 256 + threadIdx.x) * 4;
    const int k = (int)(i0 >> 8);   // D=256, float4 stays within one row

    const float4 st = *(const float4*)(mt_out + i0);
    const float4 mt = *(const float4*)(mt_in + i0);
    float4 mnew;
    mnew.x = GAMMA_F * mt.x + st.x;
    mnew.y = GAMMA_F * mt.y + st.y;
    mnew.z = GAMMA_F * mt.z + st.z;
    mnew.w = GAMMA_F * mt.w + st.w;
    *(float4*)(mt_out + i0) = mnew;

    const float Nn = (nt_new[k] + EPS_F) * n / (n + (float)KN * EPS_F);
    float4 e;
    e.x = mnew.x / Nn;
    e.y = mnew.y / Nn;
    e.z = mnew.z / Nn;
    e.w = mnew.w / Nn;
    *(float4*)(emb_out + i0) = e;
}

// ---------------------------------------------------------------------------
extern "C" void kernel_launch(void* const* d_in, const int* in_sizes, int n_in,
                              void* d_out, int out_size, void* d_ws, size_t ws_size,
                              hipStream_t stream) {
    const float* ze = (const float*)d_in[0];
    const float* W  = (const float*)d_in[1];
    const float* mt = (const float*)d_in[2];
    const float* Nt = (const float*)d_in[3];

    float* out    = (float*)d_out;
    float* zq_out = out + OFF_ZQ;
    float* commit = out + OFF_COMMIT;
    float* idxf   = out + OFF_IDX;
    float* emb    = out + OFF_EMB;
    float* mtn    = out + OFF_MT;
    float* ntn    = out + OFF_NT;

    // 1) ||w||^2 into the Nt output region (used as scratch until memset below)
    wsq_kernel<<<KN, 64, 0, stream>>>(W, ntn);

    // 2) fused distance + argmin -> indices (as float) into output
    argmin_kernel<<<NN / TM, 256, 0, stream>>>(ze, W, ntn, idxf);

    // 3) zero the accumulation regions (stream-ordered; ntn scratch consumed)
    hipMemsetAsync(commit, 0, sizeof(float), stream);
    hipMemsetAsync(mtn, 0, sizeof(float) * (size_t)KN * DD, stream);
    hipMemsetAsync(ntn, 0, sizeof(float) * KN, stream);

    // 4) gather + commit loss + one-hot scatter
    gather_scatter_kernel<<<NN / 4, 256, 0, stream>>>(ze, W, idxf, zq_out,
                                                      commit, mtn, ntn);

    // 5) EMA blend for Nt
    finalize_nt_kernel<<<KN / 256, 256, 0, stream>>>(Nt, ntn);

    // 6) mt_new, n, Nn, embedW_new
    final_kernel<<<(KN * DD / 4) / 256, 256, 0, stream>>>(mt, ntn, mtn, emb);
}

// Round 3
// 827.543 us; speedup vs baseline: 3.5329x; 3.5329x over previous
//
#include <hip/hip_runtime.h>
#include <cstddef>
#include <cstdint>

#define GAMMA_F 0.99f
#define OMG_F   0.01f      // 1 - gamma
#define EPS_F   1e-5f
#define KN 8192
#define DD 256
#define NN 32768           // B*T

// output layout (float offsets)
#define OFF_ZQ     0
#define OFF_COMMIT 8388608
#define OFF_IDX    8388609
#define OFF_EMB    8421377
#define OFF_MT     10518529
#define OFF_NT     12615681

typedef _Float16 half8 __attribute__((ext_vector_type(8)));
typedef _Float16 half4 __attribute__((ext_vector_type(4)));
typedef float    f32x4 __attribute__((ext_vector_type(4)));

// ---------------------------------------------------------------------------
// async 16B global->LDS (direct DMA: lane i -> lds_base + i*16; lds_base must
// be wave-uniform, global address must be 16B aligned)
__device__ __forceinline__ void gload16(const void* g, void* l) {
    __builtin_amdgcn_global_load_lds(
        (const __attribute__((address_space(1))) unsigned int*)g,
        (__attribute__((address_space(3))) unsigned int*)l, 16, 0, 0);
}

// sortable pack: (monotone f32 bits << 32) | idx  -> u64 min == (dist, idx) min
__device__ __forceinline__ unsigned long long packdi(float dist, int n) {
    unsigned u = __float_as_uint(dist);
    u ^= (unsigned)((int)u >> 31) | 0x80000000u;
    return ((unsigned long long)u << 32) | (unsigned)n;
}

// ---------------------------------------------------------------------------
// fp32 -> (f16 hi, f16 lo) split: x = hi + lo + O(x*2^-22)
__global__ __launch_bounds__(256) void convert_split_kernel(
    const float* __restrict__ x, _Float16* __restrict__ hi,
    _Float16* __restrict__ lo) {
    const size_t i0 = ((size_t)blockIdx.x * 256 + threadIdx.x) * 4;
    const float4 v = *(const float4*)(x + i0);
    half4 h, l;
    float f[4] = {v.x, v.y, v.z, v.w};
#pragma unroll
    for (int j = 0; j < 4; j++) {
        _Float16 hh = (_Float16)f[j];          // RNE
        float r = f[j] - (float)hh;            // exact (Sterbenz)
        h[j] = hh;
        l[j] = (_Float16)r;
    }
    *(half4*)(hi + i0) = h;
    *(half4*)(lo + i0) = l;
}

// ---------------------------------------------------------------------------
// ||w_k||^2 per code (fp32)
__global__ __launch_bounds__(64) void wsq_kernel(const float* __restrict__ W,
                                                 float* __restrict__ wsq) {
    const int k = blockIdx.x;
    const int lane = threadIdx.x;
    const float4 v = *(const float4*)(W + (size_t)k * DD + lane * 4);
    float s = v.x * v.x + v.y * v.y + v.z * v.z + v.w * v.w;
#pragma unroll
    for (int off = 32; off > 0; off >>= 1) s += __shfl_down(s, off, 64);
    if (lane == 0) wsq[k] = s;
}

// ---------------------------------------------------------------------------
// MFMA distance-GEMM + argmin.
// 128 points x 128 codes per block, virtual K = 3*256 = 768 (hh, lh, hl)
// Block = 256 threads = 4 waves in 2x2; each wave: 4x4 of 16x16x32 f16 MFMA.
// LDS tiles 128x64 f16, XOR-swizzled 16B k-chunks (DMA-linear, conflict-free).
__global__ __launch_bounds__(256) void argmin_mfma_kernel(
    const _Float16* __restrict__ zh, const _Float16* __restrict__ zl,
    const _Float16* __restrict__ wh, const _Float16* __restrict__ wl,
    const float* __restrict__ wsq, unsigned long long* __restrict__ cells) {
    __shared__ __align__(16) char smem[33792];   // tiles (32KB) / cand (33792B)
    _Float16* As = (_Float16*)smem;              // 128*64 halfs = 16 KB
    _Float16* Bs = As + 128 * 64;                // 16 KB

    const int tid  = threadIdx.x;
    const int wave = tid >> 6;
    const int lane = tid & 63;
    const int quad = lane >> 4;
    const int col  = lane & 15;
    const int wm = (wave >> 1) * 64;
    const int wn = (wave & 1) * 64;

    const int bm = blockIdx.x >> 6;
    const int bn = blockIdx.x & 63;
    const int m0 = bm * 128;
    const int n0 = bn * 128;

    f32x4 acc[4][4];
#pragma unroll
    for (int i = 0; i < 4; i++)
#pragma unroll
        for (int j = 0; j < 4; j++) acc[i][j] = (f32x4){0.f, 0.f, 0.f, 0.f};

    for (int c = 0; c < 12; ++c) {           // 12 chunks of 64 over K=768
        const int s = c >> 2;
        const int d0 = (c & 3) * 64;
        const _Float16* Ab = (s == 1) ? zl : zh;   // hh, lh, hl passes
        const _Float16* Bb = (s == 2) ? wl : wh;

        __syncthreads();
#pragma unroll
        for (int i = 0; i < 4; ++i) {
            const int clin = (wave * 4 + i) * 64 + lane;   // 0..1023
            const int mrow = clin >> 3;
            const int p = clin & 7;
            const int q = p ^ (mrow & 7);                  // swizzled k-chunk
            gload16(Ab + (size_t)(m0 + mrow) * DD + d0 + q * 8,
                    As + (wave * 4 + i) * 512);
            gload16(Bb + (size_t)(n0 + mrow) * DD + d0 + q * 8,
                    Bs + (wave * 4 + i) * 512);
        }
        __syncthreads();

#pragma unroll
        for (int kk = 0; kk < 2; ++kk) {
            half8 a[4], b[4];
#pragma unroll
            for (int t = 0; t < 4; ++t) {
                const int mr = wm + t * 16 + col;
                const int nr = wn + t * 16 + col;
                const int cc = kk * 4 + quad;
                a[t] = *(const half8*)(As + mr * 64 + (cc ^ (mr & 7)) * 8);
                b[t] = *(const half8*)(Bs + nr * 64 + (cc ^ (nr & 7)) * 8);
            }
#pragma unroll
            for (int ti = 0; ti < 4; ++ti)
#pragma unroll
                for (int tj = 0; tj < 4; ++tj)
                    acc[ti][tj] = __builtin_amdgcn_mfma_f32_16x16x32_f16(
                        a[ti], b[tj], acc[ti][tj], 0, 0, 0);
        }
    }

    // epilogue: dist = wsq - 2*dot ; lexicographic (dist, idx) min
    float wq[4];
#pragma unroll
    for (int tj = 0; tj < 4; ++tj) wq[tj] = wsq[n0 + wn + tj * 16 + col];

    __syncthreads();                         // tiles dead; reuse smem as cand
    unsigned long long* cand = (unsigned long long*)smem;  // [128][33] u64
    const int ccol = col + 16 * (wave & 1);
#pragma unroll
    for (int ti = 0; ti < 4; ++ti) {
#pragma unroll
        for (int v = 0; v < 4; ++v) {
            unsigned long long best = ~0ull;
#pragma unroll
            for (int tj = 0; tj < 4; ++tj) {
                const float dist = fmaf(-2.0f, acc[ti][tj][v], wq[tj]);
                const unsigned long long pk =
                    packdi(dist, n0 + wn + tj * 16 + col);
                best = best < pk ? best : pk;
            }
            const int m = wm + ti * 16 + quad * 4 + v;
            cand[m * 33 + ccol] = best;
        }
    }
    __syncthreads();
    {
        const int m = tid >> 1;
        const int c0 = (tid & 1) * 16;
        unsigned long long best = ~0ull;
#pragma unroll
        for (int j = 0; j < 16; ++j) {
            const unsigned long long v = cand[m * 33 + c0 + j];
            best = best < v ? best : v;
        }
        const unsigned long long o =
            (unsigned long long)__shfl_xor((unsigned long long)best, 1, 64);
        best = best < o ? best : o;
        if ((tid & 1) == 0) atomicMin(&cells[m0 + m], best);
    }
}

// ---------------------------------------------------------------------------
__global__ __launch_bounds__(256) void idx_convert_kernel(
    const unsigned long long* __restrict__ cells, float* __restrict__ idxf) {
    const int i = blockIdx.x * 256 + threadIdx.x;
    idxf[i] = (float)(unsigned)(cells[i] & 0xFFFFFFFFull);
}

// ---------------------------------------------------------------------------
// Gather zq, write zq_st, commit-loss reduce, one-hot scatter (atomics).
__global__ __launch_bounds__(256) void gather_scatter_kernel(
    const float* __restrict__ ze, const float* __restrict__ W,
    const float* __restrict__ idxf, float* __restrict__ zq_out,
    float* __restrict__ commit_acc, float* __restrict__ mt_acc,
    float* __restrict__ nt_acc) {
    const int tid = threadIdx.x;
    const int n = blockIdx.x * 4 + (tid >> 6);
    const int lane = tid & 63;
    const int idx = (int)idxf[n];

    const float4 z = *(const float4*)(ze + (size_t)n * DD + lane * 4);
    const float4 w = *(const float4*)(W + (size_t)idx * DD + lane * 4);

    float4 d, o;
    d.x = w.x - z.x; d.y = w.y - z.y; d.z = w.z - z.z; d.w = w.w - z.w;
    o.x = z.x + d.x; o.y = z.y + d.y; o.z = z.z + d.z; o.w = z.w + d.w;
    *(float4*)(zq_out + (size_t)n * DD + lane * 4) = o;

    float* mp = mt_acc + (size_t)idx * DD + lane * 4;
    atomicAdd(mp + 0, OMG_F * z.x);
    atomicAdd(mp + 1, OMG_F * z.y);
    atomicAdd(mp + 2, OMG_F * z.z);
    atomicAdd(mp + 3, OMG_F * z.w);
    if (lane == 0) atomicAdd(nt_acc + idx, OMG_F);

    float c = d.x * d.x + d.y * d.y + d.z * d.z + d.w * d.w;
#pragma unroll
    for (int off = 32; off > 0; off >>= 1) c += __shfl_down(c, off, 64);

    __shared__ float wsum[4];
    if (lane == 0) wsum[tid >> 6] = c;
    __syncthreads();
    if (tid == 0) {
        const float part = wsum[0] + wsum[1] + wsum[2] + wsum[3];
        atomicAdd(commit_acc, part * (1.0f / 8388608.0f));
    }
}

// ---------------------------------------------------------------------------
__global__ __launch_bounds__(256) void finalize_nt_kernel(
    const float* __restrict__ Nt_in, float* __restrict__ nt_acc) {
    const int k = blockIdx.x * 256 + threadIdx.x;
    nt_acc[k] += GAMMA_F * Nt_in[k];
}

// ---------------------------------------------------------------------------
__global__ __launch_bounds__(256) void final_kernel(
    const float* __restrict__ mt_in, const float* __restrict__ nt_new,
    float* __restrict__ mt_out, float* __restrict__ emb_out) {
    __shared__ float red[256];
    float s = 0.0f;
    for (int i = threadIdx.x; i < KN; i += 256) s += nt_new[i];
    red[threadIdx.x] = s;
    __syncthreads();
    for (int off = 128; off > 0; off >>= 1) {
        if (threadIdx.x < off) red[threadIdx.x] += red[threadIdx.x + off];
        __syncthreads();
    }
    const float n = red[0];

    const size_t i0 = ((size_t)blockIdx.x * 256 + threadIdx.x) * 4;
    const int k = (int)(i0 >> 8);

    const float4 st = *(const float4*)(mt_out + i0);
    const float4 mt = *(const float4*)(mt_in + i0);
    float4 mnew;
    mnew.x = GAMMA_F * mt.x + st.x;
    mnew.y = GAMMA_F * mt.y + st.y;
    mnew.z = GAMMA_F * mt.z + st.z;
    mnew.w = GAMMA_F * mt.w + st.w;
    *(float4*)(mt_out + i0) = mnew;

    const float Nn = (nt_new[k] + EPS_F) * n / (n + (float)KN * EPS_F);
    float4 e;
    e.x = mnew.x / Nn;
    e.y = mnew.y / Nn;
    e.z = mnew.z / Nn;
    e.w = mnew.w / Nn;
    *(float4*)(emb_out + i0) = e;
}

// ---------------------------------------------------------------------------
extern "C" void kernel_launch(void* const* d_in, const int* in_sizes, int n_in,
                              void* d_out, int out_size, void* d_ws, size_t ws_size,
                              hipStream_t stream) {
    const float* ze = (const float*)d_in[0];
    const float* W  = (const float*)d_in[1];
    const float* mt = (const float*)d_in[2];
    const float* Nt = (const float*)d_in[3];

    float* out    = (float*)d_out;
    float* zq_out = out + OFF_ZQ;
    float* commit = out + OFF_COMMIT;
    float* idxf   = out + OFF_IDX;
    float* emb    = out + OFF_EMB;
    float* mtn    = out + OFF_MT;
    float* ntn    = out + OFF_NT;

    // ---- scratch aliases (ALL 16B/8B aligned; consumed before final writes)
    // zh/zl: zq region (byte 0 / 16777216 — 16B aligned)
    _Float16* zh = (_Float16*)zq_out;            // NN*DD halfs
    _Float16* zl = zh + (size_t)NN * DD;
    // wh/wl: mt region +3 floats => byte 42074128 (16B aligned);
    // tail spills 3 floats into nt region (dead until memset below)
    _Float16* wh = (_Float16*)(mtn + 3);         // KN*DD halfs
    _Float16* wl = wh + (size_t)KN * DD;
    // wsq: idx region (scalar float reads; overwritten by idx_convert later)
    float* wsqbuf = idxf;                        // KN floats
    // cells: emb region +1 float => byte 33685512 (8B aligned), NN u64
    unsigned long long* cells = (unsigned long long*)(emb + 1);

    // 1) exact f16 hi/lo splits
    convert_split_kernel<<<(NN * DD / 4) / 256, 256, 0, stream>>>(ze, zh, zl);
    convert_split_kernel<<<(KN * DD / 4) / 256, 256, 0, stream>>>(W, wh, wl);

    // 2) ||w||^2 (fp32) into idx region scratch
    wsq_kernel<<<KN, 64, 0, stream>>>(W, wsqbuf);

    // 3) init argmin cells to u64-max
    hipMemsetAsync(cells, 0xFF, sizeof(unsigned long long) * NN, stream);

    // 4) MFMA distance + argmin (atomicMin of packed (dist, idx))
    argmin_mfma_kernel<<<(NN / 128) * (KN / 128), 256, 0, stream>>>(
        zh, zl, wh, wl, wsqbuf, cells);

    // 5) unpack winning indices (overwrites wsq scratch — already consumed)
    idx_convert_kernel<<<NN / 256, 256, 0, stream>>>(cells, idxf);

    // 6) zero accumulation regions (kills wh/wl scratch + 3-float spill)
    hipMemsetAsync(commit, 0, sizeof(float), stream);
    hipMemsetAsync(mtn, 0, sizeof(float) * (size_t)KN * DD, stream);
    hipMemsetAsync(ntn, 0, sizeof(float) * KN, stream);

    // 7) gather + commit loss + one-hot scatter (overwrites zh/zl with zq_st)
    gather_scatter_kernel<<<NN / 4, 256, 0, stream>>>(ze, W, idxf, zq_out,
                                                      commit, mtn, ntn);

    // 8) EMA blend for Nt
    finalize_nt_kernel<<<KN / 256, 256, 0, stream>>>(Nt, ntn);

    // 9) mt_new, n, Nn, embedW_new (overwrites cells scratch)
    final_kernel<<<(KN * DD / 4) / 256, 256, 0, stream>>>(mt, ntn, mtn, emb);
}